// Round 17
// baseline (91.887 us; speedup 1.0000x reference)
//
#include <hip/hip_runtime.h>
#include <math.h>

#define BB 8
#define CIN 256
#define HW 4096
#define BHW 32768          // B*HW
#define COUT 256
#define KTOT 2304          // CIN*9
#define WS_N (BB*9*HW)     // 294912 floats per param array

#define ACC_OFF   (4*WS_N + 64512)
#define XT_OFF    (ACC_OFF + 27*BHW)  // xT [B][HW][CIN] f16
#define NEED3     ((size_t)(XT_OFF + (BB*HW*CIN)/2) * 4)
#define WO16_OFF  (XT_OFF + (BB*HW*CIN)/2)   // wo16: 72 x 1024 f16
#define NEED4     ((size_t)(WO16_OFF + 36864) * 4)

#define PQ 520             // B_lds q-row stride (elements)
#define NK2 36             // 72 k-steps, 2 per barrier window

typedef _Float16 hf;
typedef __attribute__((ext_vector_type(8))) _Float16 hfx8;
typedef __attribute__((ext_vector_type(4))) float f32x4;

// ---------------- fused prep: xpose (2048) | wconv (256) | wprep2 (72) ----------------
__global__ __launch_bounds__(256) void prep_kernel(
    const float* __restrict__ x, const float* __restrict__ w_dcn,
    const float* __restrict__ w_off,
    hf* __restrict__ xt, hf* __restrict__ w16, hf* __restrict__ wo16)
{
  __shared__ float t[64][65];
  const int bx = blockIdx.x;
  const int tid = threadIdx.x;

  if (bx < 2048) {
    const int b  = bx >> 8;
    const int cb = (bx & 255) >> 6;
    const int pb = bx & 63;
    const int hi = tid >> 6, lo = tid & 63;
#pragma unroll
    for (int r = 0; r < 16; ++r) {
      int ci = r * 4 + hi;
      t[ci][lo] = x[((size_t)(b * 256 + cb * 64 + ci)) * HW + pb * 64 + lo];
    }
    __syncthreads();
#pragma unroll
    for (int r = 0; r < 16; ++r) {
      int p = r * 4 + hi;
      xt[((size_t)(b * HW + pb * 64 + p)) * 256 + cb * 64 + lo] = (hf)t[lo][p];
    }
  } else if (bx < 2048 + 256) {
    const int co = bx - 2048;
    const int c  = tid;
    const int cblk = c >> 5, cin = c & 31, q = cin >> 3, j = cin & 7;
#pragma unroll
    for (int kk = 0; kk < 9; ++kk)
      w16[(size_t)(cblk * 9 + kk) * 8192 + (q * 256 + co) * 8 + j] =
        (hf)w_dcn[(size_t)co * KTOT + c * 9 + kk];
  } else {
    const int ks = bx - 2304;
    const int cblk = ks / 9, kk = ks - cblk * 9;
    for (int idx = tid; idx < 1024; idx += 256) {
      int lk = idx >> 8, row = (idx >> 3) & 31, j = idx & 7;
      int c = cblk * 32 + lk * 8 + j;
      float v = (row < 27) ? w_off[(size_t)row * KTOT + c * 9 + kk] : 0.f;
      wo16[(size_t)ks * 1024 + idx] = (hf)v;
    }
  }
}

// ---------------- dcn_fused2: 128-pos block = two lockstep 64-pos halves ----------------
// 256 blocks, 512 thr (8 waves). Half hh = tid>>8 runs the v16 pipeline on its own
// 64-pos sub-tile with its own LDS regions; both halves read identical A addresses
// (L1-merged) -> per-block A L2 traffic amortized over 128 pos.
__global__ __launch_bounds__(512, 2) void dcn_fused2_kernel(
    const hf* __restrict__ xt, const hf* __restrict__ w16,
    const hf* __restrict__ wo16, const float* __restrict__ b_off,
    const float* __restrict__ b_dcn, float* __restrict__ out)
{
  __shared__ hf B_lds[2][2][8 * PQ];   // [half][buf][..]  33.3 KB (stage aliases here)
  __shared__ int2   pidx[2][576];      // 9.2 KB
  __shared__ float4 pwts[2][576];      // 18.4 KB

  const int tid  = threadIdx.x;
  const int b    = blockIdx.x & 7;
  const int pos0 = (blockIdx.x >> 3) * 128;

  const int hh   = tid >> 8;           // half 0/1
  const int t8   = tid & 255;
  const int pos0h = pos0 + hh * 64;

  const int lane = tid & 63;
  const int wid4 = (tid >> 6) & 3;     // wave index within half (co slice / phase1 pos grp)
  const int lm = lane & 15, lk = lane >> 4;
  const int gp = t8 >> 2;              // pos 0..63 within half
  const int gh = t8 & 3;               // 8-ch chunk / q
  const int gpos = pos0h + gp;
  const int gho = gpos >> 6, gwo = gpos & 63;

  const hf* bt = xt + (size_t)b * HW * 256;
  const hfx8 zv = {};

  // ================= Phase 1: offset conv (per half) =================
  {
    f32x4 oacc[2];
    oacc[0] = (f32x4){0.f, 0.f, 0.f, 0.f};
    oacc[1] = (f32x4){0.f, 0.f, 0.f, 0.f};
    const hf* wga = wo16 + ((lk * 32 + lm) << 3);

    hfx8 gA, gB;
    bool vA, vB;

#define OG(S, T, CB)                                                     \
    {                                                                    \
      int ky = (T) / 3, kx = (T) - 3 * (ky);                             \
      int yy = gho + ky - 1, xx = gwo + kx - 1;                          \
      v##S = ((unsigned)yy < 64u) && ((unsigned)xx < 64u);               \
      int row = gpos + (ky - 1) * 64 + (kx - 1);                         \
      row = min(max(row, 0), HW - 1);                                    \
      g##S = *(const hfx8*)(bt + ((size_t)row << 8) + (CB) + gh * 8);    \
    }

    OG(A, 0, 0); OG(B, 1, 0);
    *(hfx8*)&B_lds[hh][0][gh * PQ + gp * 8]       = vA ? gA : zv;
    *(hfx8*)&B_lds[hh][0][(4 + gh) * PQ + gp * 8] = vB ? gB : zv;
    OG(A, 2, 0); OG(B, 3, 0);
    asm volatile("s_waitcnt lgkmcnt(0)" ::: "memory");
    __builtin_amdgcn_sched_barrier(0);
    __builtin_amdgcn_s_barrier();

#pragma unroll 2
    for (int i = 0; i < NK2 - 1; ++i) {
      const int ri = i & 1, wi = ri ^ 1;
      const hf* wg0 = wga + (size_t)(2 * i) * 1024;
      hfx8 af00 = *(const hfx8*)(wg0);
      hfx8 af01 = *(const hfx8*)(wg0 + 128);
      hfx8 af10 = *(const hfx8*)(wg0 + 1024);
      hfx8 af11 = *(const hfx8*)(wg0 + 1024 + 128);

      hfx8 bf0 = *(const hfx8*)&B_lds[hh][ri][lk * PQ + (wid4 * 16 + lm) * 8];
      hfx8 bf1 = *(const hfx8*)&B_lds[hh][ri][(4 + lk) * PQ + (wid4 * 16 + lm) * 8];

      *(hfx8*)&B_lds[hh][wi][gh * PQ + gp * 8]       = vA ? gA : zv;
      *(hfx8*)&B_lds[hh][wi][(4 + gh) * PQ + gp * 8] = vB ? gB : zv;

      {
        int ks0 = 2 * i + 4; if (ks0 > 70) ks0 = 70;
        int dA = ks0 / 9; int tA = ks0 - dA * 9; int cbA = dA * 32;
        int ks1 = ks0 + 1;
        int dB = ks1 / 9; int tB = ks1 - dB * 9; int cbB = dB * 32;
        OG(A, tA, cbA); OG(B, tB, cbB);
      }

      oacc[0] = __builtin_amdgcn_mfma_f32_16x16x32_f16(af00, bf0, oacc[0], 0, 0, 0);
      oacc[1] = __builtin_amdgcn_mfma_f32_16x16x32_f16(af01, bf0, oacc[1], 0, 0, 0);
      oacc[0] = __builtin_amdgcn_mfma_f32_16x16x32_f16(af10, bf1, oacc[0], 0, 0, 0);
      oacc[1] = __builtin_amdgcn_mfma_f32_16x16x32_f16(af11, bf1, oacc[1], 0, 0, 0);

      asm volatile("s_waitcnt lgkmcnt(0)" ::: "memory");
      __builtin_amdgcn_sched_barrier(0);
      __builtin_amdgcn_s_barrier();
    }

    {
      const hf* wg0 = wga + (size_t)70 * 1024;
      hfx8 af00 = *(const hfx8*)(wg0);
      hfx8 af01 = *(const hfx8*)(wg0 + 128);
      hfx8 af10 = *(const hfx8*)(wg0 + 1024);
      hfx8 af11 = *(const hfx8*)(wg0 + 1024 + 128);
      hfx8 bf0 = *(const hfx8*)&B_lds[hh][1][lk * PQ + (wid4 * 16 + lm) * 8];
      hfx8 bf1 = *(const hfx8*)&B_lds[hh][1][(4 + lk) * PQ + (wid4 * 16 + lm) * 8];
      oacc[0] = __builtin_amdgcn_mfma_f32_16x16x32_f16(af00, bf0, oacc[0], 0, 0, 0);
      oacc[1] = __builtin_amdgcn_mfma_f32_16x16x32_f16(af01, bf0, oacc[1], 0, 0, 0);
      oacc[0] = __builtin_amdgcn_mfma_f32_16x16x32_f16(af10, bf1, oacc[0], 0, 0, 0);
      oacc[1] = __builtin_amdgcn_mfma_f32_16x16x32_f16(af11, bf1, oacc[1], 0, 0, 0);
    }
#undef OG

    // ---- transform: oacc -> stage (aliased into this half's B_lds) -> pidx/pwts
    float* stage = (float*)&B_lds[hh][0][0];   // 32 x 65 floats = 8.3 KB (fits 16.6 KB)
    __syncthreads();
#pragma unroll
    for (int fr = 0; fr < 2; ++fr)
#pragma unroll
      for (int r = 0; r < 4; ++r)
        stage[(fr * 16 + lk * 4 + r) * 65 + wid4 * 16 + lm] = oacc[fr][r];
    __syncthreads();
    for (int t = t8; t < 576; t += 256) {
      int kk = t >> 6, p = t & 63;
      int pos = pos0h + p;
      int ho = pos >> 6, wo = pos & 63;
      float sy = stage[(2 * kk) * 65 + p]     + b_off[2 * kk]     + (float)(ho - 1 + kk / 3);
      float sx = stage[(2 * kk + 1) * 65 + p] + b_off[2 * kk + 1] + (float)(wo - 1 + kk % 3);
      float mv = stage[(18 + kk) * 65 + p]    + b_off[18 + kk];
      float m  = 1.f / (1.f + expf(-mv));
      float y0f = floorf(sy), x0f = floorf(sx);
      int y0 = (int)y0f, x0 = (int)x0f;
      float wy = sy - y0f, wx = sx - x0f;
      int ix0 = min(max(x0, 0), 63), ix1 = min(max(x0 + 1, 0), 63);
      int bx  = min(max(x0, 0), 62);
      float vx0 = (x0 >= 0  && x0 <= 63) ? 1.f : 0.f;
      float vx1 = (x0 >= -1 && x0 <= 62) ? 1.f : 0.f;
      float wx0 = (1.f - wx) * vx0, wx1 = wx * vx1;
      float a0 = (ix0 == bx     ? wx0 : 0.f) + (ix1 == bx     ? wx1 : 0.f);
      float a1 = (ix0 == bx + 1 ? wx0 : 0.f) + (ix1 == bx + 1 ? wx1 : 0.f);
      int rb0 = min(max(y0, 0), 63), rb1 = min(max(y0 + 1, 0), 63);
      float vy0 = (y0 >= 0  && y0 <= 63) ? 1.f : 0.f;
      float vy1 = (y0 >= -1 && y0 <= 62) ? 1.f : 0.f;
      float wy0m = (1.f - wy) * vy0 * m, wy1m = wy * vy1 * m;
      pidx[hh][t] = make_int2(rb0 * 64 + bx, rb1 * 64 + bx);
      pwts[hh][t] = make_float4(a0 * wy0m, a1 * wy0m, a0 * wy1m, a1 * wy1m);
    }
    __syncthreads();
  }

  // ================= Phase 2: main DCN GEMM (per half) =================
  const int chq = t8 & 3;

  f32x4 acc[4][4];
#pragma unroll
  for (int a = 0; a < 4; ++a)
#pragma unroll
    for (int c = 0; c < 4; ++c)
      acc[a][c] = (f32x4){0.f, 0.f, 0.f, 0.f};

  const hf* wga = w16 + ((lk * 256 + wid4 * 64 + lm) << 3);
  const int wA = chq * PQ + gp * 8;
  const int wB = (4 + chq) * PQ + gp * 8;

  hf hwA0, hwA1, hwA2, hwA3, hwB0, hwB1, hwB2, hwB3;
  hfx8 cA00, cA01, cA10, cA11, cB00, cB01, cB10, cB11;

#define GATH(S, T, CB)                                                   \
  {                                                                      \
    int pb = (T) * 64 + gp;                                              \
    int2 pi = pidx[hh][pb]; float4 pw = pwts[hh][pb];                    \
    hw##S##0 = (hf)pw.x; hw##S##1 = (hf)pw.y;                            \
    hw##S##2 = (hf)pw.z; hw##S##3 = (hf)pw.w;                            \
    const hf* p0 = bt + ((size_t)pi.x << 8) + (CB) + (chq << 3);         \
    const hf* p1 = bt + ((size_t)pi.y << 8) + (CB) + (chq << 3);         \
    c##S##00 = *(const hfx8*)p0; c##S##01 = *(const hfx8*)(p0 + 256);    \
    c##S##10 = *(const hfx8*)p1; c##S##11 = *(const hfx8*)(p1 + 256);    \
  }

#define COMB(S, DST)                                                     \
  {                                                                      \
    hfx8 vv = c##S##00 * hw##S##0;                                       \
    vv += c##S##01 * hw##S##1;                                           \
    vv += c##S##10 * hw##S##2;                                           \
    vv += c##S##11 * hw##S##3;                                           \
    *(hfx8*)(DST) = vv;                                                  \
  }

  GATH(A, 0, 0); GATH(B, 1, 0);
  COMB(A, &B_lds[hh][0][wA]);
  COMB(B, &B_lds[hh][0][wB]);
  GATH(A, 2, 0); GATH(B, 3, 0);
  asm volatile("s_waitcnt lgkmcnt(0)" ::: "memory");
  __builtin_amdgcn_sched_barrier(0);
  __builtin_amdgcn_s_barrier();

#pragma unroll 2
  for (int i = 0; i < NK2 - 1; ++i) {
    const int ri = i & 1, wi = ri ^ 1;

    const hf* wg0 = wga + (size_t)(2 * i) * 8192;
    hfx8 af0[4], af1[4];
#pragma unroll
    for (int fr = 0; fr < 4; ++fr) af0[fr] = *(const hfx8*)(wg0 + fr * 128);

    hfx8 bf0[4], bf1[4];
#pragma unroll
    for (int pf = 0; pf < 4; ++pf)
      bf0[pf] = *(const hfx8*)&B_lds[hh][ri][lk * PQ + (pf * 16 + lm) * 8];
#pragma unroll
    for (int fr = 0; fr < 4; ++fr) af1[fr] = *(const hfx8*)(wg0 + 8192 + fr * 128);
#pragma unroll
    for (int pf = 0; pf < 4; ++pf)
      bf1[pf] = *(const hfx8*)&B_lds[hh][ri][(4 + lk) * PQ + (pf * 16 + lm) * 8];

    COMB(A, &B_lds[hh][wi][wA]);
    COMB(B, &B_lds[hh][wi][wB]);

    {
      int ks0 = 2 * i + 4; if (ks0 > 70) ks0 = 70;
      int dA = ks0 / 9; int tA = ks0 - dA * 9; int cbA = dA * 32;
      int ks1 = ks0 + 1;
      int dB = ks1 / 9; int tB = ks1 - dB * 9; int cbB = dB * 32;
      GATH(A, tA, cbA); GATH(B, tB, cbB);
    }

#pragma unroll
    for (int fr = 0; fr < 4; ++fr)
#pragma unroll
      for (int pf = 0; pf < 4; ++pf)
        acc[fr][pf] = __builtin_amdgcn_mfma_f32_16x16x32_f16(af0[fr], bf0[pf], acc[fr][pf], 0, 0, 0);
#pragma unroll
    for (int fr = 0; fr < 4; ++fr)
#pragma unroll
      for (int pf = 0; pf < 4; ++pf)
        acc[fr][pf] = __builtin_amdgcn_mfma_f32_16x16x32_f16(af1[fr], bf1[pf], acc[fr][pf], 0, 0, 0);

    asm volatile("s_waitcnt lgkmcnt(0)" ::: "memory");
    __builtin_amdgcn_sched_barrier(0);
    __builtin_amdgcn_s_barrier();
  }

  {
    const hf* wg0 = wga + (size_t)70 * 8192;
    hfx8 af0[4], af1[4];
#pragma unroll
    for (int fr = 0; fr < 4; ++fr) af0[fr] = *(const hfx8*)(wg0 + fr * 128);
#pragma unroll
    for (int fr = 0; fr < 4; ++fr) af1[fr] = *(const hfx8*)(wg0 + 8192 + fr * 128);
    hfx8 bf0[4], bf1[4];
#pragma unroll
    for (int pf = 0; pf < 4; ++pf) {
      bf0[pf] = *(const hfx8*)&B_lds[hh][1][lk * PQ + (pf * 16 + lm) * 8];
      bf1[pf] = *(const hfx8*)&B_lds[hh][1][(4 + lk) * PQ + (pf * 16 + lm) * 8];
    }
#pragma unroll
    for (int fr = 0; fr < 4; ++fr)
#pragma unroll
      for (int pf = 0; pf < 4; ++pf)
        acc[fr][pf] = __builtin_amdgcn_mfma_f32_16x16x32_f16(af0[fr], bf0[pf], acc[fr][pf], 0, 0, 0);
#pragma unroll
    for (int fr = 0; fr < 4; ++fr)
#pragma unroll
      for (int pf = 0; pf < 4; ++pf)
        acc[fr][pf] = __builtin_amdgcn_mfma_f32_16x16x32_f16(af1[fr], bf1[pf], acc[fr][pf], 0, 0, 0);
  }
#undef GATH
#undef COMB

  // ---- epilogue: bias + store (C/D: col=lane&15, row=(lane>>4)*4+reg)
#pragma unroll
  for (int fr = 0; fr < 4; ++fr) {
#pragma unroll
    for (int r = 0; r < 4; ++r) {
      int co = wid4 * 64 + fr * 16 + lk * 4 + r;
      float bias = b_dcn[co];
      float* orow = out + ((size_t)b * COUT + co) * HW + pos0h;
#pragma unroll
      for (int pf = 0; pf < 4; ++pf)
        orow[pf * 16 + lm] = acc[fr][pf][r] + bias;
    }
  }
}

extern "C" void kernel_launch(void* const* d_in, const int* in_sizes, int n_in,
                              void* d_out, int out_size, void* d_ws, size_t ws_size,
                              hipStream_t stream) {
  const float* x     = (const float*)d_in[0];
  const float* w_off = (const float*)d_in[1];
  const float* b_off = (const float*)d_in[2];
  const float* w_dcn = (const float*)d_in[3];
  const float* b_dcn = (const float*)d_in[4];
  float* out = (float*)d_out;
  float* ws  = (float*)d_ws;
  hf* w16  = (hf*)(ws + 3 * WS_N);

  hf* xt;
  hf* wo16;
  if (ws_size >= NEED4) {
    xt   = (hf*)(ws + XT_OFF);
    wo16 = (hf*)(ws + WO16_OFF);
  } else {
    xt   = (hf*)ws;                          // 8 MB (sy/sx/m arrays unused by fused path)
    wo16 = (hf*)(ws + (BB * HW * CIN) / 2);  // +144 KB; w16 at 3*WS_N still free
  }

  prep_kernel<<<2376, 256, 0, stream>>>(x, w_dcn, w_off, xt, w16, wo16);
  dcn_fused2_kernel<<<BB * (HW / 128), 512, 0, stream>>>(xt, w16, wo16, b_off, b_dcn, out);
}

// Round 18
// 82.911 us; speedup vs baseline: 1.1083x; 1.1083x over previous
//
#include <hip/hip_runtime.h>
#include <math.h>

#define BB 8
#define CIN 256
#define HW 4096
#define BHW 32768          // B*HW
#define COUT 256
#define KTOT 2304          // CIN*9
#define WS_N (BB*9*HW)     // 294912 floats per param array

#define ACC_OFF   (4*WS_N + 64512)
#define XT_OFF    (ACC_OFF + 27*BHW)  // xT [B][HW][CIN] f16
#define NEED3     ((size_t)(XT_OFF + (BB*HW*CIN)/2) * 4)
#define WO16_OFF  (XT_OFF + (BB*HW*CIN)/2)   // wo16: 72 x 1024 f16
#define NEED4     ((size_t)(WO16_OFF + 36864) * 4)

#define PQ 520             // B_lds q-row stride (elements)
#define NK2 36             // 72 k-steps, 2 per barrier window

typedef _Float16 hf;
typedef __attribute__((ext_vector_type(8))) _Float16 hfx8;
typedef __attribute__((ext_vector_type(4))) float f32x4;

// ---------------- fused prep: xpose (2048) | wconv (256) | wprep2 (72) ----------------
__global__ __launch_bounds__(256) void prep_kernel(
    const float* __restrict__ x, const float* __restrict__ w_dcn,
    const float* __restrict__ w_off,
    hf* __restrict__ xt, hf* __restrict__ w16, hf* __restrict__ wo16)
{
  __shared__ float t[64][65];
  const int bx = blockIdx.x;
  const int tid = threadIdx.x;

  if (bx < 2048) {
    const int b  = bx >> 8;
    const int cb = (bx & 255) >> 6;
    const int pb = bx & 63;
    const int hi = tid >> 6, lo = tid & 63;
#pragma unroll
    for (int r = 0; r < 16; ++r) {
      int ci = r * 4 + hi;
      t[ci][lo] = x[((size_t)(b * 256 + cb * 64 + ci)) * HW + pb * 64 + lo];
    }
    __syncthreads();
#pragma unroll
    for (int r = 0; r < 16; ++r) {
      int p = r * 4 + hi;
      xt[((size_t)(b * HW + pb * 64 + p)) * 256 + cb * 64 + lo] = (hf)t[lo][p];
    }
  } else if (bx < 2048 + 256) {
    const int co = bx - 2048;
    const int c  = tid;
    const int cblk = c >> 5, cin = c & 31, q = cin >> 3, j = cin & 7;
#pragma unroll
    for (int kk = 0; kk < 9; ++kk)
      w16[(size_t)(cblk * 9 + kk) * 8192 + (q * 256 + co) * 8 + j] =
        (hf)w_dcn[(size_t)co * KTOT + c * 9 + kk];
  } else {
    const int ks = bx - 2304;
    const int cblk = ks / 9, kk = ks - cblk * 9;
    for (int idx = tid; idx < 1024; idx += 256) {
      int lk = idx >> 8, row = (idx >> 3) & 31, j = idx & 7;
      int c = cblk * 32 + lk * 8 + j;
      float v = (row < 27) ? w_off[(size_t)row * KTOT + c * 9 + kk] : 0.f;
      wo16[(size_t)ks * 1024 + idx] = (hf)v;
    }
  }
}

// ---------------- dcn_fused: offconv phase + transform + dcn phase ----------------
// 512 blocks, 256 thr (4 waves). Block = (b, pos0 64-pos tile).
// Phase 1: 27(->32) x 2304 offset GEMM for own tile -> sy/sx/m -> pidx/pwts (all in LDS).
// Phase 2: v12 main loop (HWC gather + packed-f16 combine + MFMA, 4x4 acc).
__global__ __launch_bounds__(256, 2) void dcn_fused_kernel(
    const hf* __restrict__ xt, const hf* __restrict__ w16,
    const hf* __restrict__ wo16, const float* __restrict__ b_off,
    const float* __restrict__ b_dcn, float* __restrict__ out)
{
  __shared__ hf B_lds[2][8 * PQ];      // 16.6 KB (phase transition aliases stage here)
  __shared__ int2   pidx[576];
  __shared__ float4 pwts[576];

  const int tid  = threadIdx.x;
  const int b    = blockIdx.x & 7;
  const int pos0 = (blockIdx.x >> 3) * 64;

  const int lane = tid & 63, wid = tid >> 6;
  const int lm = lane & 15, lk = lane >> 4;
  const int gp = tid >> 2;                     // pos 0..63
  const int gh = tid & 3;                      // 8-ch chunk / q
  const int gpos = pos0 + gp;
  const int gho = gpos >> 6, gwo = gpos & 63;

  const hf* bt = xt + (size_t)b * HW * 256;
  const hfx8 zv = {};

  // ================= Phase 1: offset conv =================
  {
    f32x4 oacc[2];
    oacc[0] = (f32x4){0.f, 0.f, 0.f, 0.f};
    oacc[1] = (f32x4){0.f, 0.f, 0.f, 0.f};
    const hf* wga = wo16 + ((lk * 32 + lm) << 3);

    hfx8 gA, gB;
    bool vA, vB;

#define OG(S, T, CB)                                                     \
    {                                                                    \
      int ky = (T) / 3, kx = (T) - 3 * (ky);                             \
      int yy = gho + ky - 1, xx = gwo + kx - 1;                          \
      v##S = ((unsigned)yy < 64u) && ((unsigned)xx < 64u);               \
      int row = gpos + (ky - 1) * 64 + (kx - 1);                         \
      row = min(max(row, 0), HW - 1);                                    \
      g##S = *(const hfx8*)(bt + ((size_t)row << 8) + (CB) + gh * 8);    \
    }

    OG(A, 0, 0); OG(B, 1, 0);
    *(hfx8*)&B_lds[0][gh * PQ + gp * 8]       = vA ? gA : zv;
    *(hfx8*)&B_lds[0][(4 + gh) * PQ + gp * 8] = vB ? gB : zv;
    OG(A, 2, 0); OG(B, 3, 0);
    asm volatile("s_waitcnt lgkmcnt(0)" ::: "memory");
    __builtin_amdgcn_sched_barrier(0);
    __builtin_amdgcn_s_barrier();

#pragma unroll 2
    for (int i = 0; i < NK2 - 1; ++i) {
      const int ri = i & 1, wi = ri ^ 1;
      const hf* wg0 = wga + (size_t)(2 * i) * 1024;
      hfx8 af00 = *(const hfx8*)(wg0);
      hfx8 af01 = *(const hfx8*)(wg0 + 128);
      hfx8 af10 = *(const hfx8*)(wg0 + 1024);
      hfx8 af11 = *(const hfx8*)(wg0 + 1024 + 128);

      hfx8 bf0 = *(const hfx8*)&B_lds[ri][lk * PQ + (wid * 16 + lm) * 8];
      hfx8 bf1 = *(const hfx8*)&B_lds[ri][(4 + lk) * PQ + (wid * 16 + lm) * 8];

      *(hfx8*)&B_lds[wi][gh * PQ + gp * 8]       = vA ? gA : zv;
      *(hfx8*)&B_lds[wi][(4 + gh) * PQ + gp * 8] = vB ? gB : zv;

      {
        int ks0 = 2 * i + 4; if (ks0 > 70) ks0 = 70;
        int dA = ks0 / 9; int tA = ks0 - dA * 9; int cbA = dA * 32;
        int ks1 = ks0 + 1;
        int dB = ks1 / 9; int tB = ks1 - dB * 9; int cbB = dB * 32;
        OG(A, tA, cbA); OG(B, tB, cbB);
      }

      oacc[0] = __builtin_amdgcn_mfma_f32_16x16x32_f16(af00, bf0, oacc[0], 0, 0, 0);
      oacc[1] = __builtin_amdgcn_mfma_f32_16x16x32_f16(af01, bf0, oacc[1], 0, 0, 0);
      oacc[0] = __builtin_amdgcn_mfma_f32_16x16x32_f16(af10, bf1, oacc[0], 0, 0, 0);
      oacc[1] = __builtin_amdgcn_mfma_f32_16x16x32_f16(af11, bf1, oacc[1], 0, 0, 0);

      asm volatile("s_waitcnt lgkmcnt(0)" ::: "memory");
      __builtin_amdgcn_sched_barrier(0);
      __builtin_amdgcn_s_barrier();
    }

    {
      const hf* wg0 = wga + (size_t)70 * 1024;
      hfx8 af00 = *(const hfx8*)(wg0);
      hfx8 af01 = *(const hfx8*)(wg0 + 128);
      hfx8 af10 = *(const hfx8*)(wg0 + 1024);
      hfx8 af11 = *(const hfx8*)(wg0 + 1024 + 128);
      hfx8 bf0 = *(const hfx8*)&B_lds[1][lk * PQ + (wid * 16 + lm) * 8];
      hfx8 bf1 = *(const hfx8*)&B_lds[1][(4 + lk) * PQ + (wid * 16 + lm) * 8];
      oacc[0] = __builtin_amdgcn_mfma_f32_16x16x32_f16(af00, bf0, oacc[0], 0, 0, 0);
      oacc[1] = __builtin_amdgcn_mfma_f32_16x16x32_f16(af01, bf0, oacc[1], 0, 0, 0);
      oacc[0] = __builtin_amdgcn_mfma_f32_16x16x32_f16(af10, bf1, oacc[0], 0, 0, 0);
      oacc[1] = __builtin_amdgcn_mfma_f32_16x16x32_f16(af11, bf1, oacc[1], 0, 0, 0);
    }
#undef OG

    // ---- transform: acc -> stage (aliased in B_lds) -> pidx/pwts
    float* stage = (float*)&B_lds[0][0];       // [32][66] floats = 8.4 KB
    __syncthreads();
#pragma unroll
    for (int fr = 0; fr < 2; ++fr)
#pragma unroll
      for (int r = 0; r < 4; ++r)
        stage[(fr * 16 + lk * 4 + r) * 66 + wid * 16 + lm] = oacc[fr][r];
    __syncthreads();
    for (int t = tid; t < 576; t += 256) {
      int kk = t >> 6, p = t & 63;
      int pos = pos0 + p;
      int ho = pos >> 6, wo = pos & 63;
      float sy = stage[(2 * kk) * 66 + p]     + b_off[2 * kk]     + (float)(ho - 1 + kk / 3);
      float sx = stage[(2 * kk + 1) * 66 + p] + b_off[2 * kk + 1] + (float)(wo - 1 + kk % 3);
      float mv = stage[(18 + kk) * 66 + p]    + b_off[18 + kk];
      float m  = 1.f / (1.f + expf(-mv));
      float y0f = floorf(sy), x0f = floorf(sx);
      int y0 = (int)y0f, x0 = (int)x0f;
      float wy = sy - y0f, wx = sx - x0f;
      int ix0 = min(max(x0, 0), 63), ix1 = min(max(x0 + 1, 0), 63);
      int bx  = min(max(x0, 0), 62);
      float vx0 = (x0 >= 0  && x0 <= 63) ? 1.f : 0.f;
      float vx1 = (x0 >= -1 && x0 <= 62) ? 1.f : 0.f;
      float wx0 = (1.f - wx) * vx0, wx1 = wx * vx1;
      float a0 = (ix0 == bx     ? wx0 : 0.f) + (ix1 == bx     ? wx1 : 0.f);
      float a1 = (ix0 == bx + 1 ? wx0 : 0.f) + (ix1 == bx + 1 ? wx1 : 0.f);
      int rb0 = min(max(y0, 0), 63), rb1 = min(max(y0 + 1, 0), 63);
      float vy0 = (y0 >= 0  && y0 <= 63) ? 1.f : 0.f;
      float vy1 = (y0 >= -1 && y0 <= 62) ? 1.f : 0.f;
      float wy0m = (1.f - wy) * vy0 * m, wy1m = wy * vy1 * m;
      pidx[t] = make_int2(rb0 * 64 + bx, rb1 * 64 + bx);
      pwts[t] = make_float4(a0 * wy0m, a1 * wy0m, a0 * wy1m, a1 * wy1m);
    }
    __syncthreads();
  }

  // ================= Phase 2: main DCN GEMM (v12) =================
  const int chq = tid & 3;

  f32x4 acc[4][4];
#pragma unroll
  for (int a = 0; a < 4; ++a)
#pragma unroll
    for (int c = 0; c < 4; ++c)
      acc[a][c] = (f32x4){0.f, 0.f, 0.f, 0.f};

  const hf* wga = w16 + ((lk * 256 + wid * 64 + lm) << 3);
  const int wA = chq * PQ + gp * 8;
  const int wB = (4 + chq) * PQ + gp * 8;

  hf hwA0, hwA1, hwA2, hwA3, hwB0, hwB1, hwB2, hwB3;
  hfx8 cA00, cA01, cA10, cA11, cB00, cB01, cB10, cB11;

#define GATH(S, T, CB)                                                   \
  {                                                                      \
    int pb = (T) * 64 + gp;                                              \
    int2 pi = pidx[pb]; float4 pw = pwts[pb];                            \
    hw##S##0 = (hf)pw.x; hw##S##1 = (hf)pw.y;                            \
    hw##S##2 = (hf)pw.z; hw##S##3 = (hf)pw.w;                            \
    const hf* p0 = bt + ((size_t)pi.x << 8) + (CB) + (chq << 3);         \
    const hf* p1 = bt + ((size_t)pi.y << 8) + (CB) + (chq << 3);         \
    c##S##00 = *(const hfx8*)p0; c##S##01 = *(const hfx8*)(p0 + 256);    \
    c##S##10 = *(const hfx8*)p1; c##S##11 = *(const hfx8*)(p1 + 256);    \
  }

#define COMB(S, DST)                                                     \
  {                                                                      \
    hfx8 vv = c##S##00 * hw##S##0;                                       \
    vv += c##S##01 * hw##S##1;                                           \
    vv += c##S##10 * hw##S##2;                                           \
    vv += c##S##11 * hw##S##3;                                           \
    *(hfx8*)(DST) = vv;                                                  \
  }

  GATH(A, 0, 0); GATH(B, 1, 0);
  COMB(A, &B_lds[0][wA]);
  COMB(B, &B_lds[0][wB]);
  GATH(A, 2, 0); GATH(B, 3, 0);
  asm volatile("s_waitcnt lgkmcnt(0)" ::: "memory");
  __builtin_amdgcn_sched_barrier(0);
  __builtin_amdgcn_s_barrier();

#pragma unroll 2
  for (int i = 0; i < NK2 - 1; ++i) {
    const int ri = i & 1, wi = ri ^ 1;

    const hf* wg0 = wga + (size_t)(2 * i) * 8192;
    hfx8 af0[4], af1[4];
#pragma unroll
    for (int fr = 0; fr < 4; ++fr) af0[fr] = *(const hfx8*)(wg0 + fr * 128);

    hfx8 bf0[4], bf1[4];
#pragma unroll
    for (int pf = 0; pf < 4; ++pf)
      bf0[pf] = *(const hfx8*)&B_lds[ri][lk * PQ + (pf * 16 + lm) * 8];
#pragma unroll
    for (int fr = 0; fr < 4; ++fr) af1[fr] = *(const hfx8*)(wg0 + 8192 + fr * 128);
#pragma unroll
    for (int pf = 0; pf < 4; ++pf)
      bf1[pf] = *(const hfx8*)&B_lds[ri][(4 + lk) * PQ + (pf * 16 + lm) * 8];

    COMB(A, &B_lds[wi][wA]);
    COMB(B, &B_lds[wi][wB]);

    {
      int ks0 = 2 * i + 4; if (ks0 > 70) ks0 = 70;
      int dA = ks0 / 9; int tA = ks0 - dA * 9; int cbA = dA * 32;
      int ks1 = ks0 + 1;
      int dB = ks1 / 9; int tB = ks1 - dB * 9; int cbB = dB * 32;
      GATH(A, tA, cbA); GATH(B, tB, cbB);
    }

#pragma unroll
    for (int fr = 0; fr < 4; ++fr)
#pragma unroll
      for (int pf = 0; pf < 4; ++pf)
        acc[fr][pf] = __builtin_amdgcn_mfma_f32_16x16x32_f16(af0[fr], bf0[pf], acc[fr][pf], 0, 0, 0);
#pragma unroll
    for (int fr = 0; fr < 4; ++fr)
#pragma unroll
      for (int pf = 0; pf < 4; ++pf)
        acc[fr][pf] = __builtin_amdgcn_mfma_f32_16x16x32_f16(af1[fr], bf1[pf], acc[fr][pf], 0, 0, 0);

    asm volatile("s_waitcnt lgkmcnt(0)" ::: "memory");
    __builtin_amdgcn_sched_barrier(0);
    __builtin_amdgcn_s_barrier();
  }

  {
    const hf* wg0 = wga + (size_t)70 * 8192;
    hfx8 af0[4], af1[4];
#pragma unroll
    for (int fr = 0; fr < 4; ++fr) af0[fr] = *(const hfx8*)(wg0 + fr * 128);
#pragma unroll
    for (int fr = 0; fr < 4; ++fr) af1[fr] = *(const hfx8*)(wg0 + 8192 + fr * 128);
    hfx8 bf0[4], bf1[4];
#pragma unroll
    for (int pf = 0; pf < 4; ++pf) {
      bf0[pf] = *(const hfx8*)&B_lds[1][lk * PQ + (pf * 16 + lm) * 8];
      bf1[pf] = *(const hfx8*)&B_lds[1][(4 + lk) * PQ + (pf * 16 + lm) * 8];
    }
#pragma unroll
    for (int fr = 0; fr < 4; ++fr)
#pragma unroll
      for (int pf = 0; pf < 4; ++pf)
        acc[fr][pf] = __builtin_amdgcn_mfma_f32_16x16x32_f16(af0[fr], bf0[pf], acc[fr][pf], 0, 0, 0);
#pragma unroll
    for (int fr = 0; fr < 4; ++fr)
#pragma unroll
      for (int pf = 0; pf < 4; ++pf)
        acc[fr][pf] = __builtin_amdgcn_mfma_f32_16x16x32_f16(af1[fr], bf1[pf], acc[fr][pf], 0, 0, 0);
  }
#undef GATH
#undef COMB

  // ---- epilogue: bias + store (C/D: col=lane&15, row=(lane>>4)*4+reg)
#pragma unroll
  for (int fr = 0; fr < 4; ++fr) {
#pragma unroll
    for (int r = 0; r < 4; ++r) {
      int co = wid * 64 + fr * 16 + lk * 4 + r;
      float bias = b_dcn[co];
      float* orow = out + ((size_t)b * COUT + co) * HW + pos0;
#pragma unroll
      for (int pf = 0; pf < 4; ++pf)
        orow[pf * 16 + lm] = acc[fr][pf][r] + bias;
    }
  }
}

extern "C" void kernel_launch(void* const* d_in, const int* in_sizes, int n_in,
                              void* d_out, int out_size, void* d_ws, size_t ws_size,
                              hipStream_t stream) {
  const float* x     = (const float*)d_in[0];
  const float* w_off = (const float*)d_in[1];
  const float* b_off = (const float*)d_in[2];
  const float* w_dcn = (const float*)d_in[3];
  const float* b_dcn = (const float*)d_in[4];
  float* out = (float*)d_out;
  float* ws  = (float*)d_ws;
  hf* w16  = (hf*)(ws + 3 * WS_N);

  hf* xt;
  hf* wo16;
  if (ws_size >= NEED4) {
    xt   = (hf*)(ws + XT_OFF);
    wo16 = (hf*)(ws + WO16_OFF);
  } else {
    xt   = (hf*)ws;                          // 8 MB (sy/sx/m arrays unused by fused path)
    wo16 = (hf*)(ws + (BB * HW * CIN) / 2);  // +144 KB; w16 at 3*WS_N still free
  }

  prep_kernel<<<2376, 256, 0, stream>>>(x, w_dcn, w_off, xt, w16, wo16);
  dcn_fused_kernel<<<BB * (HW / 64), 256, 0, stream>>>(xt, w16, wo16, b_off, b_dcn, out);
}